// Round 8
// baseline (587.452 us; speedup 1.0000x reference)
//
#include <hip/hip_runtime.h>
#include <hip/hip_fp16.h>

#define N_NODES 50000
#define N_EDGES 800000

typedef short  bf16x8 __attribute__((ext_vector_type(8)));
typedef float  f32x4  __attribute__((ext_vector_type(4)));
typedef _Float16 h16x2 __attribute__((ext_vector_type(2)));

// 32-bit fixed point in d_out: scale 2^22.
// |per-edge contrib| <= ~3 -> iv <= 1.3e7; in-degree <= ~45 -> |sum| <= 5.7e8
// < 2^31 (4x headroom). Quantization 45 * 2^-23 ~ 5e-6, invisible under the
// bf16-path error (0.0156). Integer atomics are associative+commutative and
// per-edge values schedule-independent => bitwise-deterministic (tripwire).
#define FXP32_SCALE 4194304.0f                 // 2^22
#define FXP32_INV   2.384185791015625e-07f     // 2^-22

#define WSB_BYTES   (36864 * 2)                // 73,728 B

__device__ __forceinline__ unsigned short f2bf(float f) {
    unsigned u = __float_as_uint(f);
    u += 0x7FFF + ((u >> 16) & 1);          // RNE
    return (unsigned short)(u >> 16);
}

__device__ __forceinline__ f32x4 fma4(f32x4 a, f32x4 b, f32x4 c) {
    f32x4 r;
    r[0] = fmaf(a[0], b[0], c[0]);
    r[1] = fmaf(a[1], b[1], c[1]);
    r[2] = fmaf(a[2], b[2], c[2]);
    r[3] = fmaf(a[3], b[3], c[3]);
    return r;
}

#if __has_builtin(__builtin_amdgcn_fdot2)
__device__ __forceinline__ float FDOT2(h16x2 a, h16x2 b, float c) {
    return __builtin_amdgcn_fdot2(a, b, c, false);
}
#else
__device__ __forceinline__ float FDOT2(h16x2 a, h16x2 b, float c) {
    return fmaf((float)a.x, (float)b.x, fmaf((float)a.y, (float)b.y, c));
}
#endif

// ---------------------------------------------------------------------------
// setup: zero d_out (grid-stride) + pack W2 into bf16 B-frag order + pack W1
// into f16 k-pairs. One launch replaces the old zero+prep pair.
// B-frag (nt,ks): lane L holds B[k=ks*32+(L>>4)*8+j][n=nt*16+(L&15)], j=0..7.
// w1p[kk*64+i] = {f16(W1[2kk][i]), f16(W1[2kk+1][i])}.
// ---------------------------------------------------------------------------
__global__ void setup_kernel(const float* __restrict__ W2,
                             const float* __restrict__ W1,
                             unsigned short* __restrict__ wsB,
                             unsigned* __restrict__ w1p,
                             int4* __restrict__ out, int n16) {
    int gid = blockIdx.x * 256 + threadIdx.x;
    for (int i = gid; i < n16; i += gridDim.x * 256)
        out[i] = make_int4(0, 0, 0, 0);
    if (gid < 36864) {
        int j    = gid & 7;
        int lane = (gid >> 3) & 63;
        int ks   = (gid >> 9) & 1;
        int nt   = gid >> 10;
        int k = ks * 32 + (lane >> 4) * 8 + j;
        int n = nt * 16 + (lane & 15);
        wsB[gid] = f2bf(W2[k * 576 + n]);
    } else if (gid < 36864 + 512) {
        int idx = gid - 36864;
        int kk  = idx >> 6;
        int i   = idx & 63;
        __half lo = __float2half(W1[(2*kk)     * 64 + i]);
        __half hi = __float2half(W1[(2*kk + 1) * 64 + i]);
        w1p[idx] = (unsigned)__half_as_ushort(lo)
                 | ((unsigned)__half_as_ushort(hi) << 16);
    }
}

// ---------------------------------------------------------------------------
// finalize: in-place int32 fxp -> float in d_out. SINGLE pointer type +
// bitcast: no aliasing UB (round-1's dual-__restrict__ in-place kernel was
// the suspected cause of the 0.107 absmax failure).
// ---------------------------------------------------------------------------
__global__ void finalize_kernel(float4* p, int n4) {
    int i = blockIdx.x * blockDim.x + threadIdx.x;
    if (i < n4) {
        float4 v = p[i];
        float4 f;
        f.x = (float)__float_as_int(v.x) * FXP32_INV;
        f.y = (float)__float_as_int(v.y) * FXP32_INV;
        f.z = (float)__float_as_int(v.z) * FXP32_INV;
        f.w = (float)__float_as_int(v.w) * FXP32_INV;
        p[i] = f;
    }
}

// ---------------------------------------------------------------------------
// fused conv. v8 = v7 body verbatim, repackaged as 1-wave (64-thread) blocks:
// per-wave regions were already fully independent (no __syncthreads), so
// 9216 B LDS/block allows up to 16 blocks/CU -- fine-grained wave packing
// (old 4-wave blocks measured only ~2.6 blocks/CU resident). Epilogue emits
// int32 fixed-point atomics directly into d_out.
// ---------------------------------------------------------------------------
__global__ __launch_bounds__(64, 4) void conv_kernel(
    const float* __restrict__ pos,
    const float* __restrict__ f_in,
    const int*   __restrict__ esrc,
    const int*   __restrict__ edst,
    const unsigned* __restrict__ w1p,
    const unsigned short* __restrict__ wsB,
    int*         __restrict__ f_out_i)
{
    // 9216 B region, reused in phases (wave-local lgkmcnt only):
    //   ph1: h-stage 64x72 bf16 (stride 144 B)          = 9216 B
    //   ph2: x0t 16x64 f32 [0,4096) + dott 8x64 [4096,6144)
    //   ph3: x1t 24x64 f32 [0,6144)
    //   ph4: E1 out0+sh+dst, stride 20 f32              = 5120 B
    //   ph5: E2 out1-fused+dst, stride 28 f32           = 7168 B
    __shared__ __align__(16) char smem[9216];

    const int lane = threadIdx.x;
    const int e    = blockIdx.x * 64 + lane;
    char*  my  = smem;
    float* shf = (float*)smem;

    const int s = esrc[e];
    const int d = edst[e];

    // early B prefetch: chunks 0 and 1
    const bf16x8* wsBv = (const bf16x8*)wsB;
    bf16x8 bc0 = wsBv[lane],        bc1 = wsBv[64 + lane];
    bf16x8 bn0 = wsBv[128 + lane],  bn1 = wsBv[192 + lane];
    bf16x8 b20, b21;

    // --- geometry -----------------------------------------------------------
    float px = pos[3*d+0] - pos[3*s+0];
    float py = pos[3*d+1] - pos[3*s+1];
    float pz = pos[3*d+2] - pos[3*s+2];
    float r  = sqrtf(px*px + py*py + pz*pz + 1e-12f);
    float inv_r = __builtin_amdgcn_rcpf(r);
    float ux = px*inv_r, uy = py*inv_r, uz = pz*inv_r;
    const float SQ3 = 1.7320508075688772f;
    float shx = SQ3*ux, shy = SQ3*uy, shz = SQ3*uz;

    // --- x = f_in[src] ------------------------------------------------------
    float x0[16], x1[24], dot[8];
    {
        const float4* xg4 = reinterpret_cast<const float4*>(f_in + (size_t)s * 40);
        float xr[40];
        #pragma unroll
        for (int q8 = 0; q8 < 10; ++q8) {
            float4 v = xg4[q8];
            xr[4*q8+0] = v.x; xr[4*q8+1] = v.y; xr[4*q8+2] = v.z; xr[4*q8+3] = v.w;
        }
        #pragma unroll
        for (int i = 0; i < 16; ++i) x0[i] = xr[i];
        #pragma unroll
        for (int i = 0; i < 24; ++i) x1[i] = xr[16+i];
        #pragma unroll
        for (int u = 0; u < 8; ++u)
            dot[u] = x1[3*u+0]*ux + x1[3*u+1]*uy + x1[3*u+2]*uz;  // = inv_s3*(x1.sh1)
    }

    // --- radial embedding (dense, verified) ---------------------------------
    const float A = 1.14136f * 7.38905609893065f;   // 1.14136 * e^2
    const float inv_step = 17.0f / 5.0f;
    float emb[16];
    #pragma unroll
    for (int k = 0; k < 16; ++k) {
        float dd  = r * inv_step - (float)(k + 1);
        float d2v = dd * dd;
        float arg = -2.0f * __builtin_amdgcn_rcpf(1.0f - d2v);
        float val = A * __expf(arg);
        emb[k] = (d2v < 1.0f) ? val : 0.0f;
    }

    // --- h = silu(emb @ W1) via f16 dot2 (verified v7) -----------------------
    unsigned ep[8];
    #pragma unroll
    for (int kk = 0; kk < 8; ++kk) {
        __half lo = __float2half(emb[2*kk]);
        __half hi = __float2half(emb[2*kk+1]);
        ep[kk] = (unsigned)__half_as_ushort(lo)
               | ((unsigned)__half_as_ushort(hi) << 16);
    }
    float h[64];
    #pragma unroll
    for (int i = 0; i < 64; ++i) h[i] = 0.f;
    #pragma unroll
    for (int kk = 0; kk < 8; ++kk) {
        h16x2 ev = __builtin_bit_cast(h16x2, ep[kk]);
        const unsigned* wrow = w1p + kk * 64;
        #pragma unroll
        for (int i = 0; i < 64; ++i) {
            h16x2 wv = __builtin_bit_cast(h16x2, wrow[i]);
            h[i] = FDOT2(ev, wv, h[i]);
        }
    }
    #pragma unroll
    for (int i = 0; i < 64; ++i) {
        float z = h[i];
        h[i] = z * __builtin_amdgcn_rcpf(1.0f + __expf(-z));
    }

    // --- stage h -> LDS [edge][k] bf16, row stride 144 B -------------------
    {
        unsigned int hp[32];
        #pragma unroll
        for (int i = 0; i < 32; ++i)
            hp[i] = (unsigned)f2bf(h[2*i]) | ((unsigned)f2bf(h[2*i+1]) << 16);
        uint4* hrow = (uint4*)(my + lane * 144);
        #pragma unroll
        for (int g = 0; g < 8; ++g)
            hrow[g] = make_uint4(hp[4*g], hp[4*g+1], hp[4*g+2], hp[4*g+3]);
    }
    asm volatile("s_waitcnt lgkmcnt(0)" ::: "memory");

    // --- A fragments --------------------------------------------------------
    const int q   = lane >> 4;
    const int col = lane & 15;
    const int q4  = q * 4;
    const int ucol = col >> 3;     // u-parity for w01/w10 paths
    bf16x8 aF[4][2];
    #pragma unroll
    for (int mt = 0; mt < 4; ++mt)
        #pragma unroll
        for (int ks = 0; ks < 2; ++ks)
            aF[mt][ks] = *(const bf16x8*)(my + (mt*16 + col)*144 + q*16 + ks*64);
    asm volatile("s_waitcnt lgkmcnt(0)" ::: "memory");   // aF reads done before overwrite

    // --- stage x0t + dott (h region now dead) ------------------------------
    #pragma unroll
    for (int u = 0; u < 16; ++u) shf[u*64 + lane] = x0[u];
    #pragma unroll
    for (int u = 0; u < 8;  ++u) shf[1024 + u*64 + lane] = dot[u];
    asm volatile("s_waitcnt lgkmcnt(0)" ::: "memory");

    // --- distributed accumulators (C-layout: lane has edges 4q+r, col) ------
    f32x4 out0d[4], t01d[4], o1bd[4][3];
    #pragma unroll
    for (int m = 0; m < 4; ++m) {
        out0d[m] = (f32x4){0.f,0.f,0.f,0.f};
        t01d[m]  = (f32x4){0.f,0.f,0.f,0.f};
        #pragma unroll
        for (int k = 0; k < 3; ++k) o1bd[m][k] = (f32x4){0.f,0.f,0.f,0.f};
    }

#define MFMA8() \
    f32x4 wr0 = {0.f,0.f,0.f,0.f}, wr1 = {0.f,0.f,0.f,0.f}; \
    f32x4 wr2 = {0.f,0.f,0.f,0.f}, wr3 = {0.f,0.f,0.f,0.f}; \
    wr0 = __builtin_amdgcn_mfma_f32_16x16x32_bf16(aF[0][0], bc0, wr0, 0,0,0); \
    wr1 = __builtin_amdgcn_mfma_f32_16x16x32_bf16(aF[1][0], bc0, wr1, 0,0,0); \
    wr2 = __builtin_amdgcn_mfma_f32_16x16x32_bf16(aF[2][0], bc0, wr2, 0,0,0); \
    wr3 = __builtin_amdgcn_mfma_f32_16x16x32_bf16(aF[3][0], bc0, wr3, 0,0,0); \
    wr0 = __builtin_amdgcn_mfma_f32_16x16x32_bf16(aF[0][1], bc1, wr0, 0,0,0); \
    wr1 = __builtin_amdgcn_mfma_f32_16x16x32_bf16(aF[1][1], bc1, wr1, 0,0,0); \
    wr2 = __builtin_amdgcn_mfma_f32_16x16x32_bf16(aF[2][1], bc1, wr2, 0,0,0); \
    wr3 = __builtin_amdgcn_mfma_f32_16x16x32_bf16(aF[3][1], bc1, wr3, 0,0,0);

#define PRE(NT2) { b20 = wsBv[(NT2)*128 + lane]; b21 = wsBv[(NT2)*128 + 64 + lane]; }
#define ROT()    { bc0 = bn0; bc1 = bn1; bn0 = b20; bn1 = b21; }

// broadcast-read 4 x f32x4 from xT row BASEW and fma into ACC[0..3]
#define CONS4(ACC, BASEW) { \
    const float* xb_ = shf + (BASEW) + q4; \
    ACC[0] = fma4(wr0, *(const f32x4*)(xb_ +  0), ACC[0]); \
    ACC[1] = fma4(wr1, *(const f32x4*)(xb_ + 16), ACC[1]); \
    ACC[2] = fma4(wr2, *(const f32x4*)(xb_ + 32), ACC[2]); \
    ACC[3] = fma4(wr3, *(const f32x4*)(xb_ + 48), ACC[3]); }

    // --- w00: chunks 0..15 (cols u*16+col) ---------------------------------
    #pragma unroll
    for (int u = 0; u < 16; ++u) {
        PRE(u + 2);                         // 2..17
        MFMA8();
        CONS4(out0d, u * 64);
        ROT();
    }
    // --- w01: chunks 16..23 (u = 2t+ucol, v = col&7) -----------------------
    #pragma unroll
    for (int t = 0; t < 8; ++t) {
        PRE(t < 6 ? 18 + t : 28 + (t - 6)); // 18..23, 28, 29
        MFMA8();
        CONS4(t01d, (2*t + ucol) * 64);
        ROT();
    }
    // resolve u-parity partials: lanes col and col^8 hold complementary sums
    #pragma unroll
    for (int m = 0; m < 4; ++m)
        #pragma unroll
        for (int rr = 0; rr < 4; ++rr)
            t01d[m][rr] += __shfl_xor(t01d[m][rr], 8);

    // --- w11: chunks 28..35 (cols u*16+col, scalar = dot) ------------------
    #pragma unroll
    for (int u = 0; u < 8; ++u) {
        PRE(u < 6 ? 30 + u : 24 + (u - 6)); // 30..35, 24, 25
        MFMA8();
        CONS4(out0d, 1024 + u * 64);
        ROT();
    }

    // --- restage x1t (x0t/dott dead); drain reads first --------------------
    asm volatile("s_waitcnt lgkmcnt(0)" ::: "memory");
    #pragma unroll
    for (int u = 0; u < 8; ++u)
        #pragma unroll
        for (int k = 0; k < 3; ++k)
            shf[(u*3 + k)*64 + lane] = x1[3*u + k];
    asm volatile("s_waitcnt lgkmcnt(0)" ::: "memory");

    // --- w10: chunks 24..27 (u = 2t+ucol, v = col&7, vector over k) --------
    #pragma unroll
    for (int t = 0; t < 4; ++t) {
        if (t < 2) PRE(26 + t);             // 26, 27
        MFMA8();
        const int ub = (2*t + ucol) * 192 + q4;
#define W10_MT(MT, WR) { \
        f32x4 xv0 = *(const f32x4*)(shf + ub +   0 + 16*(MT)); \
        f32x4 xv1 = *(const f32x4*)(shf + ub +  64 + 16*(MT)); \
        f32x4 xv2 = *(const f32x4*)(shf + ub + 128 + 16*(MT)); \
        o1bd[MT][0] = fma4(WR, xv0, o1bd[MT][0]); \
        o1bd[MT][1] = fma4(WR, xv1, o1bd[MT][1]); \
        o1bd[MT][2] = fma4(WR, xv2, o1bd[MT][2]); }
        W10_MT(0, wr0) W10_MT(1, wr1) W10_MT(2, wr2) W10_MT(3, wr3)
#undef W10_MT
        ROT();
    }
#undef CONS4
#undef PRE
#undef ROT
#undef MFMA8
    // resolve o1bd u-parity partials
    #pragma unroll
    for (int m = 0; m < 4; ++m)
        #pragma unroll
        for (int k = 0; k < 3; ++k)
            #pragma unroll
            for (int rr = 0; rr < 4; ++rr)
                o1bd[m][k][rr] += __shfl_xor(o1bd[m][k][rr], 8);

    // --- epilogue ----------------------------------------------------------
    const float FXP_S = (1.0f / (32.0f * 4.898979485566356f)) * FXP32_SCALE;

    // E1: out0 (v=col) + sh + dst, stride 20 words; drain w10 reads first
    asm volatile("s_waitcnt lgkmcnt(0)" ::: "memory");
    #pragma unroll
    for (int m = 0; m < 4; ++m)
        #pragma unroll
        for (int rr = 0; rr < 4; ++rr)
            shf[(16*m + 4*q + rr) * 20 + col] = out0d[m][rr];
    shf[lane*20 + 16] = shx;
    shf[lane*20 + 17] = shy;
    shf[lane*20 + 18] = shz;
    ((int*)shf)[lane*20 + 19] = d;
    asm volatile("s_waitcnt lgkmcnt(0)" ::: "memory");

    #pragma unroll 4
    for (int it = 0; it < 16; ++it) {
        int p  = it * 64 + lane;
        int ee = p >> 4;
        int c  = p & 15;
        float v = shf[ee*20 + c];
        int dd  = ((int*)shf)[ee*20 + 19];
        atomicAdd(f_out_i + (size_t)dd*40 + c, __float2int_rn(v * FXP_S));
    }

    // E2: fused out1 = t01[v]*sh[k] + o1b[v][k], 24 words + dst, stride 28
    float shr[4][4][3];
    #pragma unroll
    for (int m = 0; m < 4; ++m)
        #pragma unroll
        for (int rr = 0; rr < 4; ++rr) {
            int eb = (16*m + 4*q + rr) * 20 + 16;
            shr[m][rr][0] = shf[eb + 0];
            shr[m][rr][1] = shf[eb + 1];
            shr[m][rr][2] = shf[eb + 2];
        }
    asm volatile("s_waitcnt lgkmcnt(0)" ::: "memory");   // shr reads done before overwrite
    if (col < 8) {
        #pragma unroll
        for (int m = 0; m < 4; ++m)
            #pragma unroll
            for (int rr = 0; rr < 4; ++rr)
                #pragma unroll
                for (int k = 0; k < 3; ++k) {
                    float fv = fmaf(t01d[m][rr], shr[m][rr][k], o1bd[m][k][rr]);
                    shf[(16*m + 4*q + rr) * 28 + 3*col + k] = fv;
                }
    }
    ((int*)shf)[lane*28 + 27] = d;
    asm volatile("s_waitcnt lgkmcnt(0)" ::: "memory");

    #pragma unroll 4
    for (int it = 0; it < 24; ++it) {
        int p  = it * 64 + lane;
        int ee = (p * 10923) >> 18;      // p / 24, exact for p < 1536
        int c  = p - ee * 24;
        float v = shf[ee*28 + c];
        int dd  = ((int*)shf)[ee*28 + 27];
        atomicAdd(f_out_i + (size_t)dd*40 + 16 + c, __float2int_rn(v * FXP_S));
    }
}

extern "C" void kernel_launch(void* const* d_in, const int* in_sizes, int n_in,
                              void* d_out, int out_size, void* d_ws, size_t ws_size,
                              hipStream_t stream) {
    const float* pos  = (const float*)d_in[0];
    const float* f_in = (const float*)d_in[1];
    const int*   esrc = (const int*)  d_in[2];
    const int*   edst = (const int*)  d_in[3];
    const float* W1   = (const float*)d_in[4];
    const float* W2   = (const float*)d_in[5];
    float* out = (float*)d_out;

    unsigned short* wsB = (unsigned short*)d_ws;
    unsigned*       w1p = (unsigned*)((char*)d_ws + WSB_BYTES);

    const int nOut = N_NODES * 40;            // 2,000,000
    const int n16  = nOut / 4;                // 500,000 int4s

    // setup: zero d_out + pack W2/W1 (one launch)
    setup_kernel<<<256, 256, 0, stream>>>(W2, W1, wsB, w1p, (int4*)out, n16);

    // conv: 1-wave blocks, int32 fxp atomics into d_out
    conv_kernel<<<N_EDGES / 64, 64, 0, stream>>>(
        pos, f_in, esrc, edst, w1p, wsB, (int*)out);

    // finalize: in-place int32 -> float (single pointer, no aliasing UB)
    finalize_kernel<<<(n16 + 255) / 256, 256, 0, stream>>>((float4*)out, n16);
}

// Round 9
// 260.362 us; speedup vs baseline: 2.2563x; 2.2563x over previous
//
#include <hip/hip_runtime.h>
#include <hip/hip_fp16.h>

#define N_NODES 50000
#define N_EDGES 800000

typedef short  bf16x8 __attribute__((ext_vector_type(8)));
typedef float  f32x4  __attribute__((ext_vector_type(4)));
typedef _Float16 h16x2 __attribute__((ext_vector_type(2)));

// 32-bit fixed point in d_out: scale 2^22.
// |per-edge contrib| <= ~3 -> iv <= 1.3e7; in-degree <= ~45 -> |sum| <= 5.7e8
// < 2^31 (4x headroom). Quantization 45 * 2^-23 ~ 5e-6, invisible under the
// bf16-path error (0.0156). Integer atomics are associative+commutative and
// per-edge values schedule-independent => bitwise-deterministic (tripwire).
// VALIDATED in round 8 (passed, absmax 0.015625).
#define FXP32_SCALE 4194304.0f                 // 2^22
#define FXP32_INV   2.384185791015625e-07f     // 2^-22

#define WSB_BYTES   (36864 * 2)                // 73,728 B

__device__ __forceinline__ unsigned short f2bf(float f) {
    unsigned u = __float_as_uint(f);
    u += 0x7FFF + ((u >> 16) & 1);          // RNE
    return (unsigned short)(u >> 16);
}

__device__ __forceinline__ f32x4 fma4(f32x4 a, f32x4 b, f32x4 c) {
    f32x4 r;
    r[0] = fmaf(a[0], b[0], c[0]);
    r[1] = fmaf(a[1], b[1], c[1]);
    r[2] = fmaf(a[2], b[2], c[2]);
    r[3] = fmaf(a[3], b[3], c[3]);
    return r;
}

#if __has_builtin(__builtin_amdgcn_fdot2)
__device__ __forceinline__ float FDOT2(h16x2 a, h16x2 b, float c) {
    return __builtin_amdgcn_fdot2(a, b, c, false);
}
#else
__device__ __forceinline__ float FDOT2(h16x2 a, h16x2 b, float c) {
    return fmaf((float)a.x, (float)b.x, fmaf((float)a.y, (float)b.y, c));
}
#endif

// ---------------------------------------------------------------------------
// setup: zero d_out (grid-stride) + pack W2 into bf16 B-frag order + pack W1
// into f16 k-pairs. One launch replaces the old zero+prep pair.
// B-frag (nt,ks): lane L holds B[k=ks*32+(L>>4)*8+j][n=nt*16+(L&15)], j=0..7.
// w1p[kk*64+i] = {f16(W1[2kk][i]), f16(W1[2kk+1][i])}.
// ---------------------------------------------------------------------------
__global__ void setup_kernel(const float* __restrict__ W2,
                             const float* __restrict__ W1,
                             unsigned short* __restrict__ wsB,
                             unsigned* __restrict__ w1p,
                             int4* __restrict__ out, int n16) {
    int gid = blockIdx.x * 256 + threadIdx.x;
    for (int i = gid; i < n16; i += gridDim.x * 256)
        out[i] = make_int4(0, 0, 0, 0);
    if (gid < 36864) {
        int j    = gid & 7;
        int lane = (gid >> 3) & 63;
        int ks   = (gid >> 9) & 1;
        int nt   = gid >> 10;
        int k = ks * 32 + (lane >> 4) * 8 + j;
        int n = nt * 16 + (lane & 15);
        wsB[gid] = f2bf(W2[k * 576 + n]);
    } else if (gid < 36864 + 512) {
        int idx = gid - 36864;
        int kk  = idx >> 6;
        int i   = idx & 63;
        __half lo = __float2half(W1[(2*kk)     * 64 + i]);
        __half hi = __float2half(W1[(2*kk + 1) * 64 + i]);
        w1p[idx] = (unsigned)__half_as_ushort(lo)
                 | ((unsigned)__half_as_ushort(hi) << 16);
    }
}

// ---------------------------------------------------------------------------
// finalize: in-place int32 fxp -> float in d_out. SINGLE pointer type +
// bitcast: no aliasing UB (round-1's dual-__restrict__ in-place kernel was
// the 0.107 absmax failure; this form validated in round 8).
// ---------------------------------------------------------------------------
__global__ void finalize_kernel(float4* p, int n4) {
    int i = blockIdx.x * blockDim.x + threadIdx.x;
    if (i < n4) {
        float4 v = p[i];
        float4 f;
        f.x = (float)__float_as_int(v.x) * FXP32_INV;
        f.y = (float)__float_as_int(v.y) * FXP32_INV;
        f.z = (float)__float_as_int(v.z) * FXP32_INV;
        f.w = (float)__float_as_int(v.w) * FXP32_INV;
        p[i] = f;
    }
}

// ---------------------------------------------------------------------------
// fused conv. v9 = v8 with __launch_bounds__(64, 2).
// ROUND-8 LESSON: (64,4) made the compiler cap arch VGPRs at 64 (< the ~130
// of live state) -> massive scratch spills -> FETCH 67->826 MB, WRITE
// 250 MB->1.5 GB, 224->524 us. (64,2) gives a >=256 VGPR cap; the compiler
// allocates its natural ~130, no spills, and runtime occupancy is set by
// actual VGPR use (~4 waves/SIMD) and LDS (17 blocks/CU) -- both better
// than the 4-wave-block round 7 (2.6 blocks/CU).
// ---------------------------------------------------------------------------
__global__ __launch_bounds__(64, 2) void conv_kernel(
    const float* __restrict__ pos,
    const float* __restrict__ f_in,
    const int*   __restrict__ esrc,
    const int*   __restrict__ edst,
    const unsigned* __restrict__ w1p,
    const unsigned short* __restrict__ wsB,
    int*         __restrict__ f_out_i)
{
    // 9216 B region, reused in phases (wave-local lgkmcnt only):
    //   ph1: h-stage 64x72 bf16 (stride 144 B)          = 9216 B
    //   ph2: x0t 16x64 f32 [0,4096) + dott 8x64 [4096,6144)
    //   ph3: x1t 24x64 f32 [0,6144)
    //   ph4: E1 out0+sh+dst, stride 20 f32              = 5120 B
    //   ph5: E2 out1-fused+dst, stride 28 f32           = 7168 B
    __shared__ __align__(16) char smem[9216];

    const int lane = threadIdx.x;
    const int e    = blockIdx.x * 64 + lane;
    char*  my  = smem;
    float* shf = (float*)smem;

    const int s = esrc[e];
    const int d = edst[e];

    // early B prefetch: chunks 0 and 1
    const bf16x8* wsBv = (const bf16x8*)wsB;
    bf16x8 bc0 = wsBv[lane],        bc1 = wsBv[64 + lane];
    bf16x8 bn0 = wsBv[128 + lane],  bn1 = wsBv[192 + lane];
    bf16x8 b20, b21;

    // --- geometry -----------------------------------------------------------
    float px = pos[3*d+0] - pos[3*s+0];
    float py = pos[3*d+1] - pos[3*s+1];
    float pz = pos[3*d+2] - pos[3*s+2];
    float r  = sqrtf(px*px + py*py + pz*pz + 1e-12f);
    float inv_r = __builtin_amdgcn_rcpf(r);
    float ux = px*inv_r, uy = py*inv_r, uz = pz*inv_r;
    const float SQ3 = 1.7320508075688772f;
    float shx = SQ3*ux, shy = SQ3*uy, shz = SQ3*uz;

    // --- x = f_in[src] ------------------------------------------------------
    float x0[16], x1[24], dot[8];
    {
        const float4* xg4 = reinterpret_cast<const float4*>(f_in + (size_t)s * 40);
        float xr[40];
        #pragma unroll
        for (int q8 = 0; q8 < 10; ++q8) {
            float4 v = xg4[q8];
            xr[4*q8+0] = v.x; xr[4*q8+1] = v.y; xr[4*q8+2] = v.z; xr[4*q8+3] = v.w;
        }
        #pragma unroll
        for (int i = 0; i < 16; ++i) x0[i] = xr[i];
        #pragma unroll
        for (int i = 0; i < 24; ++i) x1[i] = xr[16+i];
        #pragma unroll
        for (int u = 0; u < 8; ++u)
            dot[u] = x1[3*u+0]*ux + x1[3*u+1]*uy + x1[3*u+2]*uz;  // = inv_s3*(x1.sh1)
    }

    // --- radial embedding (dense, verified) ---------------------------------
    const float A = 1.14136f * 7.38905609893065f;   // 1.14136 * e^2
    const float inv_step = 17.0f / 5.0f;
    float emb[16];
    #pragma unroll
    for (int k = 0; k < 16; ++k) {
        float dd  = r * inv_step - (float)(k + 1);
        float d2v = dd * dd;
        float arg = -2.0f * __builtin_amdgcn_rcpf(1.0f - d2v);
        float val = A * __expf(arg);
        emb[k] = (d2v < 1.0f) ? val : 0.0f;
    }

    // --- h = silu(emb @ W1) via f16 dot2 (verified v7) -----------------------
    unsigned ep[8];
    #pragma unroll
    for (int kk = 0; kk < 8; ++kk) {
        __half lo = __float2half(emb[2*kk]);
        __half hi = __float2half(emb[2*kk+1]);
        ep[kk] = (unsigned)__half_as_ushort(lo)
               | ((unsigned)__half_as_ushort(hi) << 16);
    }
    float h[64];
    #pragma unroll
    for (int i = 0; i < 64; ++i) h[i] = 0.f;
    #pragma unroll
    for (int kk = 0; kk < 8; ++kk) {
        h16x2 ev = __builtin_bit_cast(h16x2, ep[kk]);
        const unsigned* wrow = w1p + kk * 64;
        #pragma unroll
        for (int i = 0; i < 64; ++i) {
            h16x2 wv = __builtin_bit_cast(h16x2, wrow[i]);
            h[i] = FDOT2(ev, wv, h[i]);
        }
    }
    #pragma unroll
    for (int i = 0; i < 64; ++i) {
        float z = h[i];
        h[i] = z * __builtin_amdgcn_rcpf(1.0f + __expf(-z));
    }

    // --- stage h -> LDS [edge][k] bf16, row stride 144 B -------------------
    {
        unsigned int hp[32];
        #pragma unroll
        for (int i = 0; i < 32; ++i)
            hp[i] = (unsigned)f2bf(h[2*i]) | ((unsigned)f2bf(h[2*i+1]) << 16);
        uint4* hrow = (uint4*)(my + lane * 144);
        #pragma unroll
        for (int g = 0; g < 8; ++g)
            hrow[g] = make_uint4(hp[4*g], hp[4*g+1], hp[4*g+2], hp[4*g+3]);
    }
    asm volatile("s_waitcnt lgkmcnt(0)" ::: "memory");

    // --- A fragments --------------------------------------------------------
    const int q   = lane >> 4;
    const int col = lane & 15;
    const int q4  = q * 4;
    const int ucol = col >> 3;     // u-parity for w01/w10 paths
    bf16x8 aF[4][2];
    #pragma unroll
    for (int mt = 0; mt < 4; ++mt)
        #pragma unroll
        for (int ks = 0; ks < 2; ++ks)
            aF[mt][ks] = *(const bf16x8*)(my + (mt*16 + col)*144 + q*16 + ks*64);
    asm volatile("s_waitcnt lgkmcnt(0)" ::: "memory");   // aF reads done before overwrite

    // --- stage x0t + dott (h region now dead) ------------------------------
    #pragma unroll
    for (int u = 0; u < 16; ++u) shf[u*64 + lane] = x0[u];
    #pragma unroll
    for (int u = 0; u < 8;  ++u) shf[1024 + u*64 + lane] = dot[u];
    asm volatile("s_waitcnt lgkmcnt(0)" ::: "memory");

    // --- distributed accumulators (C-layout: lane has edges 4q+r, col) ------
    f32x4 out0d[4], t01d[4], o1bd[4][3];
    #pragma unroll
    for (int m = 0; m < 4; ++m) {
        out0d[m] = (f32x4){0.f,0.f,0.f,0.f};
        t01d[m]  = (f32x4){0.f,0.f,0.f,0.f};
        #pragma unroll
        for (int k = 0; k < 3; ++k) o1bd[m][k] = (f32x4){0.f,0.f,0.f,0.f};
    }

#define MFMA8() \
    f32x4 wr0 = {0.f,0.f,0.f,0.f}, wr1 = {0.f,0.f,0.f,0.f}; \
    f32x4 wr2 = {0.f,0.f,0.f,0.f}, wr3 = {0.f,0.f,0.f,0.f}; \
    wr0 = __builtin_amdgcn_mfma_f32_16x16x32_bf16(aF[0][0], bc0, wr0, 0,0,0); \
    wr1 = __builtin_amdgcn_mfma_f32_16x16x32_bf16(aF[1][0], bc0, wr1, 0,0,0); \
    wr2 = __builtin_amdgcn_mfma_f32_16x16x32_bf16(aF[2][0], bc0, wr2, 0,0,0); \
    wr3 = __builtin_amdgcn_mfma_f32_16x16x32_bf16(aF[3][0], bc0, wr3, 0,0,0); \
    wr0 = __builtin_amdgcn_mfma_f32_16x16x32_bf16(aF[0][1], bc1, wr0, 0,0,0); \
    wr1 = __builtin_amdgcn_mfma_f32_16x16x32_bf16(aF[1][1], bc1, wr1, 0,0,0); \
    wr2 = __builtin_amdgcn_mfma_f32_16x16x32_bf16(aF[2][1], bc1, wr2, 0,0,0); \
    wr3 = __builtin_amdgcn_mfma_f32_16x16x32_bf16(aF[3][1], bc1, wr3, 0,0,0);

#define PRE(NT2) { b20 = wsBv[(NT2)*128 + lane]; b21 = wsBv[(NT2)*128 + 64 + lane]; }
#define ROT()    { bc0 = bn0; bc1 = bn1; bn0 = b20; bn1 = b21; }

// broadcast-read 4 x f32x4 from xT row BASEW and fma into ACC[0..3]
#define CONS4(ACC, BASEW) { \
    const float* xb_ = shf + (BASEW) + q4; \
    ACC[0] = fma4(wr0, *(const f32x4*)(xb_ +  0), ACC[0]); \
    ACC[1] = fma4(wr1, *(const f32x4*)(xb_ + 16), ACC[1]); \
    ACC[2] = fma4(wr2, *(const f32x4*)(xb_ + 32), ACC[2]); \
    ACC[3] = fma4(wr3, *(const f32x4*)(xb_ + 48), ACC[3]); }

    // --- w00: chunks 0..15 (cols u*16+col) ---------------------------------
    #pragma unroll
    for (int u = 0; u < 16; ++u) {
        PRE(u + 2);                         // 2..17
        MFMA8();
        CONS4(out0d, u * 64);
        ROT();
    }
    // --- w01: chunks 16..23 (u = 2t+ucol, v = col&7) -----------------------
    #pragma unroll
    for (int t = 0; t < 8; ++t) {
        PRE(t < 6 ? 18 + t : 28 + (t - 6)); // 18..23, 28, 29
        MFMA8();
        CONS4(t01d, (2*t + ucol) * 64);
        ROT();
    }
    // resolve u-parity partials: lanes col and col^8 hold complementary sums
    #pragma unroll
    for (int m = 0; m < 4; ++m)
        #pragma unroll
        for (int rr = 0; rr < 4; ++rr)
            t01d[m][rr] += __shfl_xor(t01d[m][rr], 8);

    // --- w11: chunks 28..35 (cols u*16+col, scalar = dot) ------------------
    #pragma unroll
    for (int u = 0; u < 8; ++u) {
        PRE(u < 6 ? 30 + u : 24 + (u - 6)); // 30..35, 24, 25
        MFMA8();
        CONS4(out0d, 1024 + u * 64);
        ROT();
    }

    // --- restage x1t (x0t/dott dead); drain reads first --------------------
    asm volatile("s_waitcnt lgkmcnt(0)" ::: "memory");
    #pragma unroll
    for (int u = 0; u < 8; ++u)
        #pragma unroll
        for (int k = 0; k < 3; ++k)
            shf[(u*3 + k)*64 + lane] = x1[3*u + k];
    asm volatile("s_waitcnt lgkmcnt(0)" ::: "memory");

    // --- w10: chunks 24..27 (u = 2t+ucol, v = col&7, vector over k) --------
    #pragma unroll
    for (int t = 0; t < 4; ++t) {
        if (t < 2) PRE(26 + t);             // 26, 27
        MFMA8();
        const int ub = (2*t + ucol) * 192 + q4;
#define W10_MT(MT, WR) { \
        f32x4 xv0 = *(const f32x4*)(shf + ub +   0 + 16*(MT)); \
        f32x4 xv1 = *(const f32x4*)(shf + ub +  64 + 16*(MT)); \
        f32x4 xv2 = *(const f32x4*)(shf + ub + 128 + 16*(MT)); \
        o1bd[MT][0] = fma4(WR, xv0, o1bd[MT][0]); \
        o1bd[MT][1] = fma4(WR, xv1, o1bd[MT][1]); \
        o1bd[MT][2] = fma4(WR, xv2, o1bd[MT][2]); }
        W10_MT(0, wr0) W10_MT(1, wr1) W10_MT(2, wr2) W10_MT(3, wr3)
#undef W10_MT
        ROT();
    }
#undef CONS4
#undef PRE
#undef ROT
#undef MFMA8
    // resolve o1bd u-parity partials
    #pragma unroll
    for (int m = 0; m < 4; ++m)
        #pragma unroll
        for (int k = 0; k < 3; ++k)
            #pragma unroll
            for (int rr = 0; rr < 4; ++rr)
                o1bd[m][k][rr] += __shfl_xor(o1bd[m][k][rr], 8);

    // --- epilogue ----------------------------------------------------------
    const float FXP_S = (1.0f / (32.0f * 4.898979485566356f)) * FXP32_SCALE;

    // E1: out0 (v=col) + sh + dst, stride 20 words; drain w10 reads first
    asm volatile("s_waitcnt lgkmcnt(0)" ::: "memory");
    #pragma unroll
    for (int m = 0; m < 4; ++m)
        #pragma unroll
        for (int rr = 0; rr < 4; ++rr)
            shf[(16*m + 4*q + rr) * 20 + col] = out0d[m][rr];
    shf[lane*20 + 16] = shx;
    shf[lane*20 + 17] = shy;
    shf[lane*20 + 18] = shz;
    ((int*)shf)[lane*20 + 19] = d;
    asm volatile("s_waitcnt lgkmcnt(0)" ::: "memory");

    #pragma unroll 4
    for (int it = 0; it < 16; ++it) {
        int p  = it * 64 + lane;
        int ee = p >> 4;
        int c  = p & 15;
        float v = shf[ee*20 + c];
        int dd  = ((int*)shf)[ee*20 + 19];
        atomicAdd(f_out_i + (size_t)dd*40 + c, __float2int_rn(v * FXP_S));
    }

    // E2: fused out1 = t01[v]*sh[k] + o1b[v][k], 24 words + dst, stride 28
    float shr[4][4][3];
    #pragma unroll
    for (int m = 0; m < 4; ++m)
        #pragma unroll
        for (int rr = 0; rr < 4; ++rr) {
            int eb = (16*m + 4*q + rr) * 20 + 16;
            shr[m][rr][0] = shf[eb + 0];
            shr[m][rr][1] = shf[eb + 1];
            shr[m][rr][2] = shf[eb + 2];
        }
    asm volatile("s_waitcnt lgkmcnt(0)" ::: "memory");   // shr reads done before overwrite
    if (col < 8) {
        #pragma unroll
        for (int m = 0; m < 4; ++m)
            #pragma unroll
            for (int rr = 0; rr < 4; ++rr)
                #pragma unroll
                for (int k = 0; k < 3; ++k) {
                    float fv = fmaf(t01d[m][rr], shr[m][rr][k], o1bd[m][k][rr]);
                    shf[(16*m + 4*q + rr) * 28 + 3*col + k] = fv;
                }
    }
    ((int*)shf)[lane*28 + 27] = d;
    asm volatile("s_waitcnt lgkmcnt(0)" ::: "memory");

    #pragma unroll 4
    for (int it = 0; it < 24; ++it) {
        int p  = it * 64 + lane;
        int ee = (p * 10923) >> 18;      // p / 24, exact for p < 1536
        int c  = p - ee * 24;
        float v = shf[ee*28 + c];
        int dd  = ((int*)shf)[ee*28 + 27];
        atomicAdd(f_out_i + (size_t)dd*40 + 16 + c, __float2int_rn(v * FXP_S));
    }
}

extern "C" void kernel_launch(void* const* d_in, const int* in_sizes, int n_in,
                              void* d_out, int out_size, void* d_ws, size_t ws_size,
                              hipStream_t stream) {
    const float* pos  = (const float*)d_in[0];
    const float* f_in = (const float*)d_in[1];
    const int*   esrc = (const int*)  d_in[2];
    const int*   edst = (const int*)  d_in[3];
    const float* W1   = (const float*)d_in[4];
    const float* W2   = (const float*)d_in[5];
    float* out = (float*)d_out;

    unsigned short* wsB = (unsigned short*)d_ws;
    unsigned*       w1p = (unsigned*)((char*)d_ws + WSB_BYTES);

    const int nOut = N_NODES * 40;            // 2,000,000
    const int n16  = nOut / 4;                // 500,000 int4s

    // setup: zero d_out + pack W2/W1 (one launch)
    setup_kernel<<<256, 256, 0, stream>>>(W2, W1, wsB, w1p, (int4*)out, n16);

    // conv: 1-wave blocks, int32 fxp atomics into d_out
    conv_kernel<<<N_EDGES / 64, 64, 0, stream>>>(
        pos, f_in, esrc, edst, w1p, wsB, (int*)out);

    // finalize: in-place int32 -> float (single pointer, no aliasing UB)
    finalize_kernel<<<(n16 + 255) / 256, 256, 0, stream>>>((float4*)out, n16);
}

// Round 10
// 258.100 us; speedup vs baseline: 2.2761x; 1.0088x over previous
//
#include <hip/hip_runtime.h>

#define N_NODES 50000
#define N_EDGES 800000

typedef short  bf16x8 __attribute__((ext_vector_type(8)));
typedef float  f32x4  __attribute__((ext_vector_type(4)));

// 32-bit fixed point in d_out: scale 2^22.
// |per-edge contrib| <= ~3 -> iv <= 1.3e7; in-degree <= ~45 -> |sum| <= 5.7e8
// < 2^31 (4x headroom). Quantization ~5e-6, invisible under the bf16-path
// error (0.0156). Integer atomics are associative+commutative and per-edge
// values schedule-independent => bitwise-deterministic (tripwire).
// VALIDATED rounds 8/9.
#define FXP32_SCALE 4194304.0f                 // 2^22
#define FXP32_INV   2.384185791015625e-07f     // 2^-22

#define WSB_BYTES   (36864 * 2)                // 73,728 B
#define W1T_ENTRIES 2048                       // 4 mt-frags x 64 lanes x 8 j
#define EOFF        4608                       // emb-stage byte offset in smem

__device__ __forceinline__ unsigned short f2bf(float f) {
    unsigned u = __float_as_uint(f);
    u += 0x7FFF + ((u >> 16) & 1);          // RNE
    return (unsigned short)(u >> 16);
}

__device__ __forceinline__ unsigned pack2bf(float a, float b) {
    return (unsigned)f2bf(a) | ((unsigned)f2bf(b) << 16);
}

__device__ __forceinline__ f32x4 fma4(f32x4 a, f32x4 b, f32x4 c) {
    f32x4 r;
    r[0] = fmaf(a[0], b[0], c[0]);
    r[1] = fmaf(a[1], b[1], c[1]);
    r[2] = fmaf(a[2], b[2], c[2]);
    r[3] = fmaf(a[3], b[3], c[3]);
    return r;
}

// ---------------------------------------------------------------------------
// setup: zero d_out (grid-stride) + pack W2 into bf16 B-frag order + pack
// W1^T (zero-padded K 16->32) into bf16 A-frag order for the h-MFMA.
// B-frag (nt,ks): lane L holds B[k=ks*32+(L>>4)*8+j][n=nt*16+(L&15)], j=0..7.
// A-frag (mt):    lane L holds A[row=mt*16+(L&15)][k=(L>>4)*8+j], j=0..7,
//                 A = W1^T, i.e. A[i][k] = W1[k][i]; zero for k>=16.
// ---------------------------------------------------------------------------
__global__ void setup_kernel(const float* __restrict__ W2,
                             const float* __restrict__ W1,
                             unsigned short* __restrict__ wsB,
                             unsigned short* __restrict__ w1tf,
                             int4* __restrict__ out, int n16) {
    int gid = blockIdx.x * 256 + threadIdx.x;
    for (int i = gid; i < n16; i += gridDim.x * 256)
        out[i] = make_int4(0, 0, 0, 0);
    if (gid < 36864) {
        int j    = gid & 7;
        int lane = (gid >> 3) & 63;
        int ks   = (gid >> 9) & 1;
        int nt   = gid >> 10;
        int k = ks * 32 + (lane >> 4) * 8 + j;
        int n = nt * 16 + (lane & 15);
        wsB[gid] = f2bf(W2[k * 576 + n]);
    } else if (gid < 36864 + W1T_ENTRIES) {
        int idx  = gid - 36864;
        int j    = idx & 7;
        int lane = (idx >> 3) & 63;
        int mt   = idx >> 9;
        int k = (lane >> 4) * 8 + j;
        int n = mt * 16 + (lane & 15);            // = i (W1 column)
        w1tf[idx] = (k < 16) ? f2bf(W1[k * 64 + n]) : (unsigned short)0;
    }
}

// ---------------------------------------------------------------------------
// finalize: in-place int32 fxp -> float in d_out. SINGLE pointer type +
// bitcast: no aliasing UB (validated rounds 8/9).
// ---------------------------------------------------------------------------
__global__ void finalize_kernel(float4* p, int n4) {
    int i = blockIdx.x * blockDim.x + threadIdx.x;
    if (i < n4) {
        float4 v = p[i];
        float4 f;
        f.x = (float)__float_as_int(v.x) * FXP32_INV;
        f.y = (float)__float_as_int(v.y) * FXP32_INV;
        f.z = (float)__float_as_int(v.z) * FXP32_INV;
        f.w = (float)__float_as_int(v.w) * FXP32_INV;
        p[i] = f;
    }
}

// ---------------------------------------------------------------------------
// fused conv. v10 = v9 with h = silu(emb @ W1) moved to the matrix pipe:
// compute h^T = W1^T @ emb^T via mfma_f32_16x16x32_bf16 (K zero-padded
// 16->32; SAME frag layouts verified since round 2). Flipped orientation so
// the C-layout gives each lane 4 CONSECUTIVE i per (mt,nt) -> h rows written
// with 16 ds_write_b64 instead of 64 scalar writes. Removes the 512-dot2
// VALU h-loop (r7's biggest remaining VALU block). Everything from the aF
// reads onward is byte-identical to r9.
// ---------------------------------------------------------------------------
__global__ __launch_bounds__(64, 2) void conv_kernel(
    const float* __restrict__ pos,
    const float* __restrict__ f_in,
    const int*   __restrict__ esrc,
    const int*   __restrict__ edst,
    const unsigned short* __restrict__ w1tf,
    const unsigned short* __restrict__ wsB,
    int*         __restrict__ f_out_i)
{
    // 9216 B region, reused in phases (wave-local lgkmcnt only):
    //   ph0: emb-stage 64 edges x 32 bf16 (stride 64 B) at [EOFF, EOFF+4096)
    //   ph1: h-stage 64x72 bf16 (stride 144 B)          = 9216 B (full region)
    //   ph2: x0t 16x64 f32 [0,4096) + dott 8x64 [4096,6144)
    //   ph3: x1t 24x64 f32 [0,6144)
    //   ph4: E1 out0+sh+dst, stride 20 f32              = 5120 B
    //   ph5: E2 out1-fused+dst, stride 28 f32           = 7168 B
    __shared__ __align__(16) char smem[9216];

    const int lane = threadIdx.x;
    const int e    = blockIdx.x * 64 + lane;
    char*  my  = smem;
    float* shf = (float*)smem;

    const int s = esrc[e];
    const int d = edst[e];

    const int q   = lane >> 4;
    const int col = lane & 15;

    // early global prefetch: main-GEMM B chunks 0,1 + h-MFMA A (W1^T) frags
    const bf16x8* wsBv = (const bf16x8*)wsB;
    bf16x8 bc0 = wsBv[lane],        bc1 = wsBv[64 + lane];
    bf16x8 bn0 = wsBv[128 + lane],  bn1 = wsBv[192 + lane];
    bf16x8 b20, b21;
    const bf16x8* w1tv = (const bf16x8*)w1tf;
    bf16x8 aW[4];
    #pragma unroll
    for (int mt = 0; mt < 4; ++mt) aW[mt] = w1tv[mt * 64 + lane];

    // --- geometry -----------------------------------------------------------
    float px = pos[3*d+0] - pos[3*s+0];
    float py = pos[3*d+1] - pos[3*s+1];
    float pz = pos[3*d+2] - pos[3*s+2];
    float r  = sqrtf(px*px + py*py + pz*pz + 1e-12f);
    float inv_r = __builtin_amdgcn_rcpf(r);
    float ux = px*inv_r, uy = py*inv_r, uz = pz*inv_r;
    const float SQ3 = 1.7320508075688772f;
    float shx = SQ3*ux, shy = SQ3*uy, shz = SQ3*uz;

    // --- x = f_in[src] ------------------------------------------------------
    float x0[16], x1[24], dot[8];
    {
        const float4* xg4 = reinterpret_cast<const float4*>(f_in + (size_t)s * 40);
        float xr[40];
        #pragma unroll
        for (int q8 = 0; q8 < 10; ++q8) {
            float4 v = xg4[q8];
            xr[4*q8+0] = v.x; xr[4*q8+1] = v.y; xr[4*q8+2] = v.z; xr[4*q8+3] = v.w;
        }
        #pragma unroll
        for (int i = 0; i < 16; ++i) x0[i] = xr[i];
        #pragma unroll
        for (int i = 0; i < 24; ++i) x1[i] = xr[16+i];
        #pragma unroll
        for (int u = 0; u < 8; ++u)
            dot[u] = x1[3*u+0]*ux + x1[3*u+1]*uy + x1[3*u+2]*uz;  // = inv_s3*(x1.sh1)
    }

    // --- radial embedding (dense, verified; sparse variant abandoned) -------
    const float A = 1.14136f * 7.38905609893065f;   // 1.14136 * e^2
    const float inv_step = 17.0f / 5.0f;
    float emb[16];
    #pragma unroll
    for (int k = 0; k < 16; ++k) {
        float dd  = r * inv_step - (float)(k + 1);
        float d2v = dd * dd;
        float arg = -2.0f * __builtin_amdgcn_rcpf(1.0f - d2v);
        float val = A * __expf(arg);
        emb[k] = (d2v < 1.0f) ? val : 0.0f;
    }

    // --- stage emb -> LDS rows [edge][k] bf16, 32 cols (top 16 zero) --------
    {
        unsigned ep[8];
        #pragma unroll
        for (int kk = 0; kk < 8; ++kk) ep[kk] = pack2bf(emb[2*kk], emb[2*kk+1]);
        uint4* erow = (uint4*)(my + EOFF + lane * 64);
        erow[0] = make_uint4(ep[0], ep[1], ep[2], ep[3]);
        erow[1] = make_uint4(ep[4], ep[5], ep[6], ep[7]);
        erow[2] = make_uint4(0u, 0u, 0u, 0u);
        erow[3] = make_uint4(0u, 0u, 0u, 0u);
    }
    asm volatile("s_waitcnt lgkmcnt(0)" ::: "memory");

    // --- read emb^T B-frags (same pattern as aF reads, stride 64) -----------
    bf16x8 bE[4];
    #pragma unroll
    for (int nt = 0; nt < 4; ++nt)
        bE[nt] = *(const bf16x8*)(my + EOFF + (nt*16 + col)*64 + q*16);
    asm volatile("s_waitcnt lgkmcnt(0)" ::: "memory");   // bE in regs before h-writes clobber

    // --- h^T = W1^T @ emb^T per nt-tile: 4 MFMA -> silu -> pack -> b64 write -
    // C-layout: lane holds h[i = 16mt+4q+rr][edge = 16nt+col] -> 4 consecutive
    // i per (mt): one 8-byte write at row (16nt+col)*144 + (32mt+8q) bytes.
    #pragma unroll
    for (int nt = 0; nt < 4; ++nt) {
        f32x4 cH[4];
        #pragma unroll
        for (int mt = 0; mt < 4; ++mt) {
            f32x4 z = {0.f, 0.f, 0.f, 0.f};
            cH[mt] = __builtin_amdgcn_mfma_f32_16x16x32_bf16(aW[mt], bE[nt], z, 0, 0, 0);
        }
        char* rowb = my + (nt*16 + col) * 144 + q * 8;
        #pragma unroll
        for (int mt = 0; mt < 4; ++mt) {
            #pragma unroll
            for (int rr = 0; rr < 4; ++rr) {
                float z = cH[mt][rr];
                cH[mt][rr] = z * __builtin_amdgcn_rcpf(1.0f + __expf(-z));
            }
            unsigned lo = pack2bf(cH[mt][0], cH[mt][1]);
            unsigned hi = pack2bf(cH[mt][2], cH[mt][3]);
            *(uint2*)(rowb + mt * 32) = make_uint2(lo, hi);
        }
    }
    asm volatile("s_waitcnt lgkmcnt(0)" ::: "memory");

    // --- A fragments (byte-identical to r9 from here on) --------------------
    const int q4  = q * 4;
    const int ucol = col >> 3;     // u-parity for w01/w10 paths
    bf16x8 aF[4][2];
    #pragma unroll
    for (int mt = 0; mt < 4; ++mt)
        #pragma unroll
        for (int ks = 0; ks < 2; ++ks)
            aF[mt][ks] = *(const bf16x8*)(my + (mt*16 + col)*144 + q*16 + ks*64);
    asm volatile("s_waitcnt lgkmcnt(0)" ::: "memory");   // aF reads done before overwrite

    // --- stage x0t + dott (h region now dead) ------------------------------
    #pragma unroll
    for (int u = 0; u < 16; ++u) shf[u*64 + lane] = x0[u];
    #pragma unroll
    for (int u = 0; u < 8;  ++u) shf[1024 + u*64 + lane] = dot[u];
    asm volatile("s_waitcnt lgkmcnt(0)" ::: "memory");

    // --- distributed accumulators (C-layout: lane has edges 4q+r, col) ------
    f32x4 out0d[4], t01d[4], o1bd[4][3];
    #pragma unroll
    for (int m = 0; m < 4; ++m) {
        out0d[m] = (f32x4){0.f,0.f,0.f,0.f};
        t01d[m]  = (f32x4){0.f,0.f,0.f,0.f};
        #pragma unroll
        for (int k = 0; k < 3; ++k) o1bd[m][k] = (f32x4){0.f,0.f,0.f,0.f};
    }

#define MFMA8() \
    f32x4 wr0 = {0.f,0.f,0.f,0.f}, wr1 = {0.f,0.f,0.f,0.f}; \
    f32x4 wr2 = {0.f,0.f,0.f,0.f}, wr3 = {0.f,0.f,0.f,0.f}; \
    wr0 = __builtin_amdgcn_mfma_f32_16x16x32_bf16(aF[0][0], bc0, wr0, 0,0,0); \
    wr1 = __builtin_amdgcn_mfma_f32_16x16x32_bf16(aF[1][0], bc0, wr1, 0,0,0); \
    wr2 = __builtin_amdgcn_mfma_f32_16x16x32_bf16(aF[2][0], bc0, wr2, 0,0,0); \
    wr3 = __builtin_amdgcn_mfma_f32_16x16x32_bf16(aF[3][0], bc0, wr3, 0,0,0); \
    wr0 = __builtin_amdgcn_mfma_f32_16x16x32_bf16(aF[0][1], bc1, wr0, 0,0,0); \
    wr1 = __builtin_amdgcn_mfma_f32_16x16x32_bf16(aF[1][1], bc1, wr1, 0,0,0); \
    wr2 = __builtin_amdgcn_mfma_f32_16x16x32_bf16(aF[2][1], bc1, wr2, 0,0,0); \
    wr3 = __builtin_amdgcn_mfma_f32_16x16x32_bf16(aF[3][1], bc1, wr3, 0,0,0);

#define PRE(NT2) { b20 = wsBv[(NT2)*128 + lane]; b21 = wsBv[(NT2)*128 + 64 + lane]; }
#define ROT()    { bc0 = bn0; bc1 = bn1; bn0 = b20; bn1 = b21; }

// broadcast-read 4 x f32x4 from xT row BASEW and fma into ACC[0..3]
#define CONS4(ACC, BASEW) { \
    const float* xb_ = shf + (BASEW) + q4; \
    ACC[0] = fma4(wr0, *(const f32x4*)(xb_ +  0), ACC[0]); \
    ACC[1] = fma4(wr1, *(const f32x4*)(xb_ + 16), ACC[1]); \
    ACC[2] = fma4(wr2, *(const f32x4*)(xb_ + 32), ACC[2]); \
    ACC[3] = fma4(wr3, *(const f32x4*)(xb_ + 48), ACC[3]); }

    // --- w00: chunks 0..15 (cols u*16+col) ---------------------------------
    #pragma unroll
    for (int u = 0; u < 16; ++u) {
        PRE(u + 2);                         // 2..17
        MFMA8();
        CONS4(out0d, u * 64);
        ROT();
    }
    // --- w01: chunks 16..23 (u = 2t+ucol, v = col&7) -----------------------
    #pragma unroll
    for (int t = 0; t < 8; ++t) {
        PRE(t < 6 ? 18 + t : 28 + (t - 6)); // 18..23, 28, 29
        MFMA8();
        CONS4(t01d, (2*t + ucol) * 64);
        ROT();
    }
    // resolve u-parity partials: lanes col and col^8 hold complementary sums
    #pragma unroll
    for (int m = 0; m < 4; ++m)
        #pragma unroll
        for (int rr = 0; rr < 4; ++rr)
            t01d[m][rr] += __shfl_xor(t01d[m][rr], 8);

    // --- w11: chunks 28..35 (cols u*16+col, scalar = dot) ------------------
    #pragma unroll
    for (int u = 0; u < 8; ++u) {
        PRE(u < 6 ? 30 + u : 24 + (u - 6)); // 30..35, 24, 25
        MFMA8();
        CONS4(out0d, 1024 + u * 64);
        ROT();
    }

    // --- restage x1t (x0t/dott dead); drain reads first --------------------
    asm volatile("s_waitcnt lgkmcnt(0)" ::: "memory");
    #pragma unroll
    for (int u = 0; u < 8; ++u)
        #pragma unroll
        for (int k = 0; k < 3; ++k)
            shf[(u*3 + k)*64 + lane] = x1[3*u + k];
    asm volatile("s_waitcnt lgkmcnt(0)" ::: "memory");

    // --- w10: chunks 24..27 (u = 2t+ucol, v = col&7, vector over k) --------
    #pragma unroll
    for (int t = 0; t < 4; ++t) {
        if (t < 2) PRE(26 + t);             // 26, 27
        MFMA8();
        const int ub = (2*t + ucol) * 192 + q4;
#define W10_MT(MT, WR) { \
        f32x4 xv0 = *(const f32x4*)(shf + ub +   0 + 16*(MT)); \
        f32x4 xv1 = *(const f32x4*)(shf + ub +  64 + 16*(MT)); \
        f32x4 xv2 = *(const f32x4*)(shf + ub + 128 + 16*(MT)); \
        o1bd[MT][0] = fma4(WR, xv0, o1bd[MT][0]); \
        o1bd[MT][1] = fma4(WR, xv1, o1bd[MT][1]); \
        o1bd[MT][2] = fma4(WR, xv2, o1bd[MT][2]); }
        W10_MT(0, wr0) W10_MT(1, wr1) W10_MT(2, wr2) W10_MT(3, wr3)
#undef W10_MT
        ROT();
    }
#undef CONS4
#undef PRE
#undef ROT
#undef MFMA8
    // resolve o1bd u-parity partials
    #pragma unroll
    for (int m = 0; m < 4; ++m)
        #pragma unroll
        for (int k = 0; k < 3; ++k)
            #pragma unroll
            for (int rr = 0; rr < 4; ++rr)
                o1bd[m][k][rr] += __shfl_xor(o1bd[m][k][rr], 8);

    // --- epilogue ----------------------------------------------------------
    const float FXP_S = (1.0f / (32.0f * 4.898979485566356f)) * FXP32_SCALE;

    // E1: out0 (v=col) + sh + dst, stride 20 words; drain w10 reads first
    asm volatile("s_waitcnt lgkmcnt(0)" ::: "memory");
    #pragma unroll
    for (int m = 0; m < 4; ++m)
        #pragma unroll
        for (int rr = 0; rr < 4; ++rr)
            shf[(16*m + 4*q + rr) * 20 + col] = out0d[m][rr];
    shf[lane*20 + 16] = shx;
    shf[lane*20 + 17] = shy;
    shf[lane*20 + 18] = shz;
    ((int*)shf)[lane*20 + 19] = d;
    asm volatile("s_waitcnt lgkmcnt(0)" ::: "memory");

    #pragma unroll 4
    for (int it = 0; it < 16; ++it) {
        int p  = it * 64 + lane;
        int ee = p >> 4;
        int c  = p & 15;
        float v = shf[ee*20 + c];
        int dd  = ((int*)shf)[ee*20 + 19];
        atomicAdd(f_out_i + (size_t)dd*40 + c, __float2int_rn(v * FXP_S));
    }

    // E2: fused out1 = t01[v]*sh[k] + o1b[v][k], 24 words + dst, stride 28
    float shr[4][4][3];
    #pragma unroll
    for (int m = 0; m < 4; ++m)
        #pragma unroll
        for (int rr = 0; rr < 4; ++rr) {
            int eb = (16*m + 4*q + rr) * 20 + 16;
            shr[m][rr][0] = shf[eb + 0];
            shr[m][rr][1] = shf[eb + 1];
            shr[m][rr][2] = shf[eb + 2];
        }
    asm volatile("s_waitcnt lgkmcnt(0)" ::: "memory");   // shr reads done before overwrite
    if (col < 8) {
        #pragma unroll
        for (int m = 0; m < 4; ++m)
            #pragma unroll
            for (int rr = 0; rr < 4; ++rr)
                #pragma unroll
                for (int k = 0; k < 3; ++k) {
                    float fv = fmaf(t01d[m][rr], shr[m][rr][k], o1bd[m][k][rr]);
                    shf[(16*m + 4*q + rr) * 28 + 3*col + k] = fv;
                }
    }
    ((int*)shf)[lane*28 + 27] = d;
    asm volatile("s_waitcnt lgkmcnt(0)" ::: "memory");

    #pragma unroll 4
    for (int it = 0; it < 24; ++it) {
        int p  = it * 64 + lane;
        int ee = (p * 10923) >> 18;      // p / 24, exact for p < 1536
        int c  = p - ee * 24;
        float v = shf[ee*28 + c];
        int dd  = ((int*)shf)[ee*28 + 27];
        atomicAdd(f_out_i + (size_t)dd*40 + 16 + c, __float2int_rn(v * FXP_S));
    }
}

extern "C" void kernel_launch(void* const* d_in, const int* in_sizes, int n_in,
                              void* d_out, int out_size, void* d_ws, size_t ws_size,
                              hipStream_t stream) {
    const float* pos  = (const float*)d_in[0];
    const float* f_in = (const float*)d_in[1];
    const int*   esrc = (const int*)  d_in[2];
    const int*   edst = (const int*)  d_in[3];
    const float* W1   = (const float*)d_in[4];
    const float* W2   = (const float*)d_in[5];
    float* out = (float*)d_out;

    unsigned short* wsB  = (unsigned short*)d_ws;
    unsigned short* w1tf = (unsigned short*)((char*)d_ws + WSB_BYTES);

    const int nOut = N_NODES * 40;            // 2,000,000
    const int n16  = nOut / 4;                // 500,000 int4s

    // setup: zero d_out + pack W2 B-frags + W1^T A-frags (one launch).
    // grid must cover 36864 + 2048 = 38912 pack slots -> 152 blocks.
    setup_kernel<<<256, 256, 0, stream>>>(W2, W1, wsB, w1tf, (int4*)out, n16);

    // conv: 1-wave blocks, int32 fxp atomics into d_out
    conv_kernel<<<N_EDGES / 64, 64, 0, stream>>>(
        pos, f_in, esrc, edst, w1tf, wsB, (int*)out);

    // finalize: in-place int32 -> float (single pointer, no aliasing UB)
    finalize_kernel<<<(n16 + 255) / 256, 256, 0, stream>>>((float4*)out, n16);
}